// Round 4
// baseline (148.128 us; speedup 1.0000x reference)
//
#include <hip/hip_runtime.h>

#define NQ   10
#define NL   4
#define NST  1024     // 2^NQ
#define FFN  4096
#define EOUT 1024

__device__ __forceinline__ float2 cmul(float2 a, float2 b) {
    return make_float2(a.x * b.x - a.y * b.y, a.x * b.y + a.y * b.x);
}
__device__ __forceinline__ float2 cadd(float2 a, float2 b) {
    return make_float2(a.x + b.x, a.y + b.y);
}

// One block = full pipeline: circuit sim (redundant per block) -> z -> h -> 4 y entries.
// 256 blocks x 256 threads; block b's wave w computes y[b*4+w].
__global__ __launch_bounds__(256) void qffn_compute(
    const float* __restrict__ params,  // (NL, NQ, 3)
    const float* __restrict__ W1,      // (FFN, NQ)
    const float* __restrict__ b1,      // (FFN,)
    const float* __restrict__ W2,      // (EOUT, FFN)
    const float* __restrict__ b2,      // (EOUT,)
    float* __restrict__ y)             // (EOUT,)
{
    __shared__ float2 s[NST];                 // statevector, 8 KB
    __shared__ float2 Ug[NL * NQ][4];         // fused Rz*Ry*Rx per (l,q)
    __shared__ float  wred[4][NQ];
    __shared__ float  zsh[NQ];
    __shared__ __align__(16) float hs[FFN];   // 16 KB

    const int t = threadIdx.x;
    const int lane = t & 63;
    const int wid  = t >> 6;

    // ---- init state |0...0> and precompute fused 1q gate matrices ----
    for (int m = 0; m < 4; ++m) {
        int i = t + m * 256;
        s[i] = make_float2(i == 0 ? 1.0f : 0.0f, 0.0f);
    }
    if (t < NL * NQ) {
        float th0 = params[t * 3 + 0];
        float th1 = params[t * 3 + 1];
        float th2 = params[t * 3 + 2];
        float c0 = cosf(0.5f * th0), s0 = sinf(0.5f * th0);
        float c1 = cosf(0.5f * th1), s1 = sinf(0.5f * th1);
        float c2 = cosf(0.5f * th2), s2 = sinf(0.5f * th2);
        // M = Ry * Rx
        float2 M00 = make_float2( c1 * c0,  s1 * s0);
        float2 M01 = make_float2(-s1 * c0, -c1 * s0);
        float2 M10 = make_float2( s1 * c0, -c1 * s0);
        float2 M11 = make_float2( c1 * c0, -s1 * s0);
        float2 em = make_float2(c2, -s2);   // e^{-i th2/2}
        float2 ep = make_float2(c2,  s2);   // e^{+i th2/2}
        Ug[t][0] = cmul(em, M00);
        Ug[t][1] = cmul(em, M01);
        Ug[t][2] = cmul(ep, M10);
        Ug[t][3] = cmul(ep, M11);
    }
    __syncthreads();

    // ---- circuit: per layer, 10 fused rotations then CNOT-chain permutation ----
    for (int l = 0; l < NL; ++l) {
        for (int q = 0; q < NQ; ++q) {
            const int p = 9 - q;            // flat bit for qubit q (row-major (2,)*10)
            const int mask = 1 << p;
            const float2 U00 = Ug[l * NQ + q][0];
            const float2 U01 = Ug[l * NQ + q][1];
            const float2 U10 = Ug[l * NQ + q][2];
            const float2 U11 = Ug[l * NQ + q][3];
            // each thread owns 2 self-contained pairs -> only 1 barrier per gate
            #pragma unroll
            for (int m = 0; m < 2; ++m) {
                int pt = t + m * 256;                       // pair id in [0,512)
                int i0 = ((pt >> p) << (p + 1)) | (pt & (mask - 1));
                int i1 = i0 | mask;
                float2 a0 = s[i0], a1 = s[i1];
                float2 n0 = cadd(cmul(U00, a0), cmul(U01, a1));
                float2 n1 = cadd(cmul(U10, a0), cmul(U11, a1));
                s[i0] = n0;
                s[i1] = n1;
            }
            __syncthreads();
        }
        // CNOT chain (0,1)(1,2)...(8,9)(9,0) is GF(2)-linear: apply as one gather.
        // new[i] = old[Finv(i)]; qubit-bit c_q = bit (9-q) of i.
        float2 v[4];
        #pragma unroll
        for (int m = 0; m < 4; ++m) {
            int i = t + m * 256;
            int c[NQ], b[NQ];
            #pragma unroll
            for (int qq = 0; qq < NQ; ++qq) c[qq] = (i >> (9 - qq)) & 1;
            b[0] = c[0] ^ c[9];
            b[1] = c[1] ^ b[0];
            #pragma unroll
            for (int k = 2; k < NQ; ++k) b[k] = c[k] ^ c[k - 1];
            int src = 0;
            #pragma unroll
            for (int qq = 0; qq < NQ; ++qq) src |= b[qq] << (9 - qq);
            v[m] = s[src];
        }
        __syncthreads();
        #pragma unroll
        for (int m = 0; m < 4; ++m) s[t + m * 256] = v[m];
        __syncthreads();
    }

    // ---- expvals: z[q] = 1 - 2 * sum_{bit(9-q)=1} |amp|^2 ----
    float loc[NQ];
    #pragma unroll
    for (int q = 0; q < NQ; ++q) loc[q] = 0.0f;
    #pragma unroll
    for (int m = 0; m < 4; ++m) {
        int i = t + m * 256;
        float2 a = s[i];
        float pr = a.x * a.x + a.y * a.y;
        #pragma unroll
        for (int q = 0; q < NQ; ++q)
            if ((i >> (9 - q)) & 1) loc[q] += pr;
    }
    #pragma unroll
    for (int q = 0; q < NQ; ++q) {
        float v = loc[q];
        #pragma unroll
        for (int off = 32; off > 0; off >>= 1) v += __shfl_down(v, off, 64);
        loc[q] = v;
    }
    if (lane == 0)
        for (int q = 0; q < NQ; ++q) wred[wid][q] = loc[q];
    __syncthreads();
    if (t < NQ) {
        float p1 = wred[0][t] + wred[1][t] + wred[2][t] + wred[3][t];
        zsh[t] = 1.0f - 2.0f * p1;
    }
    __syncthreads();

    // ---- h = relu(z @ W1^T + b1), in LDS ----
    float z[NQ];
    #pragma unroll
    for (int q = 0; q < NQ; ++q) z[q] = zsh[q];
    for (int f = t; f < FFN; f += 256) {
        float acc = b1[f];
        #pragma unroll
        for (int q = 0; q < NQ; ++q) acc += z[q] * W1[f * NQ + q];
        hs[f] = fmaxf(acc, 0.0f);
    }
    __syncthreads();

    // ---- y[e] = h . W2[e,:] + b2[e]; one y entry per wave ----
    const int e = blockIdx.x * 4 + wid;
    const float4* __restrict__ W2r = (const float4*)(W2 + (size_t)e * FFN);
    const float4* __restrict__ h4 = (const float4*)hs;
    float acc = 0.0f;
    for (int j = lane; j < FFN / 4; j += 64) {
        float4 w = W2r[j];
        float4 h = h4[j];
        acc += w.x * h.x + w.y * h.y + w.z * h.z + w.w * h.w;
    }
    #pragma unroll
    for (int off = 32; off > 0; off >>= 1) acc += __shfl_down(acc, off, 64);
    if (lane == 0) y[e] = acc + b2[e];
}

// Broadcast y (1024 floats) to out (B*T copies). Stride is a multiple of
// 1024 floats so each thread's y-float4 is loop-invariant.
__global__ __launch_bounds__(256) void qffn_broadcast(
    const float* __restrict__ y, float4* __restrict__ out, int nvec)
{
    const float4* __restrict__ y4 = (const float4*)y;
    const int gtid = blockIdx.x * blockDim.x + threadIdx.x;
    const float4 val = y4[gtid & 255];
    const int stride = gridDim.x * blockDim.x;   // 524288, multiple of 256
    for (int v = gtid; v < nvec; v += stride) out[v] = val;
}

extern "C" void kernel_launch(void* const* d_in, const int* in_sizes, int n_in,
                              void* d_out, int out_size, void* d_ws, size_t ws_size,
                              hipStream_t stream) {
    // inputs: x, W_in, b_in, params, W1, b1, W2, b2 (x/W_in/b_in are dead)
    const float* params = (const float*)d_in[3];
    const float* W1     = (const float*)d_in[4];
    const float* b1     = (const float*)d_in[5];
    const float* W2     = (const float*)d_in[6];
    const float* b2     = (const float*)d_in[7];
    float* y   = (float*)d_ws;          // 1024 floats scratch
    float* out = (float*)d_out;

    qffn_compute<<<256, 256, 0, stream>>>(params, W1, b1, W2, b2, y);

    const int nvec = out_size / 4;      // 4,194,304 float4s
    qffn_broadcast<<<2048, 256, 0, stream>>>(y, (float4*)out, nvec);
}

// Round 7
// 147.877 us; speedup vs baseline: 1.0017x; 1.0017x over previous
//
#include <hip/hip_runtime.h>

#define NQ   10
#define NL   4
#define NST  1024     // 2^NQ
#define FFN  4096
#define EOUT 1024

// pad every 32 float2 by 1 to break power-of-2 bank conflicts in low-bit rounds
#define SIDX(i) ((i) + ((i) >> 5))

// native clang vector type: required by __builtin_nontemporal_store
typedef float f32x4 __attribute__((ext_vector_type(4)));

__device__ __forceinline__ float2 cmul(float2 a, float2 b) {
    return make_float2(a.x * b.x - a.y * b.y, a.x * b.y + a.y * b.x);
}
__device__ __forceinline__ float2 cadd(float2 a, float2 b) {
    return make_float2(a.x + b.x, a.y + b.y);
}

// One block = full pipeline: circuit sim (redundant per block) -> z -> h -> 4 y entries.
// 256 blocks x 256 threads; block b's wave w computes y[b*4+w].
__global__ __launch_bounds__(256) void qffn_compute(
    const float* __restrict__ params,  // (NL, NQ, 3)
    const float* __restrict__ W1,      // (FFN, NQ)
    const float* __restrict__ b1,      // (FFN,)
    const float* __restrict__ W2,      // (EOUT, FFN)
    const float* __restrict__ b2,      // (EOUT,)
    float* __restrict__ y)             // (EOUT,)
{
    __shared__ float2 s[NST + (NST >> 5)];    // padded statevector, ~8.25 KB
    __shared__ float2 Ug[NL * NQ][4];         // fused Rz*Ry*Rx per (l,q)
    __shared__ float  wred[4][NQ];
    __shared__ float  zsh[NQ];
    __shared__ __align__(16) float hs[FFN];   // 16 KB

    const int t = threadIdx.x;
    const int lane = t & 63;
    const int wid  = t >> 6;

    // ---- init state |0...0> and precompute fused 1q gate matrices ----
    for (int m = 0; m < 4; ++m) {
        int i = t + m * 256;
        s[SIDX(i)] = make_float2(i == 0 ? 1.0f : 0.0f, 0.0f);
    }
    if (t < NL * NQ) {
        float th0 = params[t * 3 + 0];
        float th1 = params[t * 3 + 1];
        float th2 = params[t * 3 + 2];
        float c0 = cosf(0.5f * th0), s0 = sinf(0.5f * th0);
        float c1 = cosf(0.5f * th1), s1 = sinf(0.5f * th1);
        float c2 = cosf(0.5f * th2), s2 = sinf(0.5f * th2);
        // M = Ry * Rx
        float2 M00 = make_float2( c1 * c0,  s1 * s0);
        float2 M01 = make_float2(-s1 * c0, -c1 * s0);
        float2 M10 = make_float2( s1 * c0, -c1 * s0);
        float2 M11 = make_float2( c1 * c0, -s1 * s0);
        float2 em = make_float2(c2, -s2);   // e^{-i th2/2}
        float2 ep = make_float2(c2,  s2);   // e^{+i th2/2}
        Ug[t][0] = cmul(em, M00);
        Ug[t][1] = cmul(em, M01);
        Ug[t][2] = cmul(ep, M10);
        Ug[t][3] = cmul(ep, M11);
    }
    __syncthreads();

    // Final-round register amps (indices 4t..4t+3 of the pre-CNOT last-layer state)
    float2 f0, f1, f2, f3;

    // ---- circuit: per layer, 5 two-qubit-gate rounds, then CNOT-chain permutation ----
    #pragma unroll
    for (int l = 0; l < NL; ++l) {
        #pragma unroll
        for (int r = 0; r < 5; ++r) {
            const int qa = 2 * r, qb = qa + 1;
            const int phi = 9 - qa;          // flat bit of qubit qa
            const int plo = phi - 1;         // flat bit of qubit qb (adjacent)
            const float2 A00 = Ug[l * NQ + qa][0], A01 = Ug[l * NQ + qa][1];
            const float2 A10 = Ug[l * NQ + qa][2], A11 = Ug[l * NQ + qa][3];
            const float2 B00 = Ug[l * NQ + qb][0], B01 = Ug[l * NQ + qb][1];
            const float2 B10 = Ug[l * NQ + qb][2], B11 = Ug[l * NQ + qb][3];
            // thread t owns the 4-amp subcube over bits {phi, plo}
            const int mlo = (1 << plo) - 1;
            const int i00 = ((t >> plo) << (plo + 2)) | (t & mlo);
            const int i01 = i00 | (1 << plo);
            const int i10 = i00 | (1 << phi);
            const int i11 = i10 | (1 << plo);
            float2 a00 = s[SIDX(i00)], a01 = s[SIDX(i01)];
            float2 a10 = s[SIDX(i10)], a11 = s[SIDX(i11)];
            // U_qa on high bit: pairs (a00,a10), (a01,a11)
            float2 n00 = cadd(cmul(A00, a00), cmul(A01, a10));
            float2 n10 = cadd(cmul(A10, a00), cmul(A11, a10));
            float2 n01 = cadd(cmul(A00, a01), cmul(A01, a11));
            float2 n11 = cadd(cmul(A10, a01), cmul(A11, a11));
            // U_qb on low bit: pairs (n00,n01), (n10,n11)
            float2 m00 = cadd(cmul(B00, n00), cmul(B01, n01));
            float2 m01 = cadd(cmul(B10, n00), cmul(B11, n01));
            float2 m10 = cadd(cmul(B00, n10), cmul(B01, n11));
            float2 m11 = cadd(cmul(B10, n10), cmul(B11, n11));
            if (l == NL - 1 && r == 4) {
                // last round of last layer: i00 = 4t; keep in registers, fold the
                // final CNOT chain into the expval bit-map (it's a permutation).
                f0 = m00; f1 = m01; f2 = m10; f3 = m11;
            } else {
                s[SIDX(i00)] = m00; s[SIDX(i01)] = m01;
                s[SIDX(i10)] = m10; s[SIDX(i11)] = m11;
                __syncthreads();
            }
        }
        if (l < NL - 1) {
            // CNOT chain (0,1)(1,2)...(8,9)(9,0) as one gather: new[i]=old[Finv(i)]
            float2 v[4];
            #pragma unroll
            for (int m = 0; m < 4; ++m) {
                int i = t + m * 256;
                int c[NQ], b[NQ];
                #pragma unroll
                for (int qq = 0; qq < NQ; ++qq) c[qq] = (i >> (9 - qq)) & 1;
                b[0] = c[0] ^ c[9];
                b[1] = c[1] ^ b[0];
                #pragma unroll
                for (int k = 2; k < NQ; ++k) b[k] = c[k] ^ c[k - 1];
                int src = 0;
                #pragma unroll
                for (int qq = 0; qq < NQ; ++qq) src |= b[qq] << (9 - qq);
                v[m] = s[SIDX(src)];
            }
            __syncthreads();
            #pragma unroll
            for (int m = 0; m < 4; ++m) s[SIDX(t + m * 256)] = v[m];
            __syncthreads();
        }
    }

    // ---- expvals with forward CNOT map folded in:
    // z[q] = 1 - 2 * sum_{c_q(F(i))=1} |amp_i|^2, amps in registers (i = 4t+k)
    float loc[NQ];
    #pragma unroll
    for (int q = 0; q < NQ; ++q) loc[q] = 0.0f;
    {
        float2 ff[4] = {f0, f1, f2, f3};
        #pragma unroll
        for (int k = 0; k < 4; ++k) {
            const int i = 4 * t + k;
            const float pr = ff[k].x * ff[k].x + ff[k].y * ff[k].y;
            int b[NQ], c[NQ];
            #pragma unroll
            for (int qq = 0; qq < NQ; ++qq) b[qq] = (i >> (9 - qq)) & 1;
            // forward chain: c1=b1^b0; ck=bk^c(k-1); c0=b0^c9
            c[1] = b[1] ^ b[0];
            #pragma unroll
            for (int k2 = 2; k2 < NQ; ++k2) c[k2] = b[k2] ^ c[k2 - 1];
            c[0] = b[0] ^ c[9];
            #pragma unroll
            for (int qq = 0; qq < NQ; ++qq)
                if (c[qq]) loc[qq] += pr;
        }
    }
    #pragma unroll
    for (int q = 0; q < NQ; ++q) {
        float v = loc[q];
        #pragma unroll
        for (int off = 32; off > 0; off >>= 1) v += __shfl_down(v, off, 64);
        loc[q] = v;
    }
    if (lane == 0)
        for (int q = 0; q < NQ; ++q) wred[wid][q] = loc[q];
    __syncthreads();
    if (t < NQ) {
        float p1 = wred[0][t] + wred[1][t] + wred[2][t] + wred[3][t];
        zsh[t] = 1.0f - 2.0f * p1;
    }
    __syncthreads();

    // ---- h = relu(z @ W1^T + b1), in LDS ----
    float z[NQ];
    #pragma unroll
    for (int q = 0; q < NQ; ++q) z[q] = zsh[q];
    for (int f = t; f < FFN; f += 256) {
        float acc = b1[f];
        #pragma unroll
        for (int q = 0; q < NQ; ++q) acc += z[q] * W1[f * NQ + q];
        hs[f] = fmaxf(acc, 0.0f);
    }
    __syncthreads();

    // ---- y[e] = h . W2[e,:] + b2[e]; one y entry per wave ----
    const int e = blockIdx.x * 4 + wid;
    const float4* __restrict__ W2r = (const float4*)(W2 + (size_t)e * FFN);
    const float4* __restrict__ h4 = (const float4*)hs;
    float acc = 0.0f;
    for (int j = lane; j < FFN / 4; j += 64) {
        float4 w = W2r[j];
        float4 h = h4[j];
        acc += w.x * h.x + w.y * h.y + w.z * h.z + w.w * h.w;
    }
    #pragma unroll
    for (int off = 32; off > 0; off >>= 1) acc += __shfl_down(acc, off, 64);
    if (lane == 0) y[e] = acc + b2[e];
}

// Broadcast y (1024 floats) to out (B*T copies). Stride is a multiple of
// 1024 floats so each thread's y-float4 is loop-invariant. Non-temporal:
// pure streaming write, no reuse (uses native vector type for the builtin).
__global__ __launch_bounds__(256) void qffn_broadcast(
    const float* __restrict__ y, f32x4* __restrict__ out, int nvec)
{
    const f32x4* __restrict__ y4 = (const f32x4*)y;
    const int gtid = blockIdx.x * blockDim.x + threadIdx.x;
    const f32x4 val = y4[gtid & 255];
    const int stride = 2048 * 256;   // 524288, multiple of 256
    for (int v = gtid; v < nvec; v += stride)
        __builtin_nontemporal_store(val, &out[v]);
}

extern "C" void kernel_launch(void* const* d_in, const int* in_sizes, int n_in,
                              void* d_out, int out_size, void* d_ws, size_t ws_size,
                              hipStream_t stream) {
    // inputs: x, W_in, b_in, params, W1, b1, W2, b2 (x/W_in/b_in are dead)
    const float* params = (const float*)d_in[3];
    const float* W1     = (const float*)d_in[4];
    const float* b1     = (const float*)d_in[5];
    const float* W2     = (const float*)d_in[6];
    const float* b2     = (const float*)d_in[7];
    float* y   = (float*)d_ws;          // 1024 floats scratch
    float* out = (float*)d_out;

    qffn_compute<<<256, 256, 0, stream>>>(params, W1, b1, W2, b2, y);

    const int nvec = out_size / 4;      // 4,194,304 float4s
    qffn_broadcast<<<2048, 256, 0, stream>>>(y, (f32x4*)out, nvec);
}